// Round 11
// baseline (249.621 us; speedup 1.0000x reference)
//
#include <hip/hip_runtime.h>

// ---------------- problem constants ----------------
#define D_MODEL 1024
#define D_STATE 16
#define D_CONV  4
#define D_INNER 2048
#define DT_RANK 16
#define BATCH   2
#define SEQ     1024
#define M_ROWS  (BATCH*SEQ)   // 2048 rows
#define CHUNK   32            // timesteps per scan chunk
#define NCHUNK  (SEQ/CHUNK)   // 32 chunks
#define XP_KSPLIT 16
#define XP_KLEN (D_INNER / XP_KSPLIT)   // 128

typedef __bf16 bf16x8 __attribute__((ext_vector_type(8)));
typedef float  f32x4  __attribute__((ext_vector_type(4)));

__device__ __forceinline__ unsigned short f2bf(float f) {
  unsigned u = __float_as_uint(f);
  u += 0x7fffu + ((u >> 16) & 1u);      // round-to-nearest-even
  return (unsigned short)(u >> 16);
}

__device__ __forceinline__ float sigmoid_fast(float v) {
  return 1.f / (1.f + __expf(-v));
}

__device__ __forceinline__ float softplus_f(float s) {
  return (s > 20.f) ? s : __logf(1.f + __expf(s));
}

// async global->LDS, 16B per lane; LDS dest is wave-uniform base + lane*16 [m97/m104]
__device__ __forceinline__ void gll16(const void* g, void* l) {
  __builtin_amdgcn_global_load_lds(
      (const __attribute__((address_space(1))) unsigned int*)g,
      (__attribute__((address_space(3))) unsigned int*)l, 16, 0, 0);
}

// epilogue store helpers (f32 or bf16 C)
__device__ __forceinline__ void storeC(float v, float* p)          { *p = v; }
__device__ __forceinline__ void storeC(float v, unsigned short* p) { *p = f2bf(v); }

// ---------------- cast f32 -> bf16 (x, in_proj_w, out_proj_w, x_proj_w) + zero dlt/Bm/Cm ----
__global__ __launch_bounds__(256) void cast_all_kernel(
    const float* __restrict__ x, const float* __restrict__ w1, const float* __restrict__ w2,
    const float* __restrict__ xpw,
    unsigned short* __restrict__ xbf, unsigned short* __restrict__ w1bf,
    unsigned short* __restrict__ w2bf, unsigned short* __restrict__ xpwbf,
    float* __restrict__ zbuf /* dlt base; dlt|Bm|Cm contiguous 384 KB */) {
  const int N0 = (M_ROWS * D_MODEL) / 4;        // 524288 float4
  const int N1 = (2 * D_INNER * D_MODEL) / 4;   // 1048576
  const int N2 = (D_MODEL * D_INNER) / 4;       // 524288
  const int N3 = (48 * D_INNER) / 4;            // 24576
  // NZ = 3 * M_ROWS * 16 / 4 = 24576 float4 (zeros for dlt/Bm/Cm)
  int i = blockIdx.x * 256 + threadIdx.x;       // grid = 8384 blocks, covers all exactly
  const float* src; unsigned short* dst; int off;
  if (i < N0)                 { src = x;   dst = xbf;   off = i; }
  else if (i < N0 + N1)       { src = w1;  dst = w1bf;  off = i - N0; }
  else if (i < N0 + N1 + N2)  { src = w2;  dst = w2bf;  off = i - N0 - N1; }
  else if (i < N0 + N1 + N2 + N3) { src = xpw; dst = xpwbf; off = i - N0 - N1 - N2; }
  else {
    float4 z = {0.f, 0.f, 0.f, 0.f};
    ((float4*)zbuf)[i - N0 - N1 - N2 - N3] = z;
    return;
  }
  float4 v = *(const float4*)(src + (size_t)off * 4);
  ushort4 o;
  o.x = f2bf(v.x); o.y = f2bf(v.y); o.z = f2bf(v.z); o.w = f2bf(v.w);
  *(ushort4*)(dst + (size_t)off * 4) = o;
}

// ---------------- bf16 MFMA GEMM with global_load_lds staging (m97 structure) ----------
// NT: C[M,N] = A[M,K] @ B[N,K]^T + bias[N]. CT = float or unsigned short (bf16 out).
// BK=64: halves the per-K-step vmcnt(0)+barrier drains vs BK=32 (32->16 / 64->32 iters);
// LDS 32KB (As+Bs) keeps >=3 blocks/CU (avoids the m132 BK=128/64KB occupancy cliff).
template<int BM, int BK, typename CT>
__global__ __launch_bounds__(256) void gemm_gll(
    const __bf16* __restrict__ A, const __bf16* __restrict__ B,
    const float* __restrict__ bias, CT* __restrict__ C,
    int M, int N, int K) {
  constexpr int MR  = BM / 32;         // M fragments per wave (2 or 4)
  constexpr int LPR = BK / 8;          // lanes per LDS row (16B each lane)
  constexpr int RPI = 64 / LPR;        // rows covered by one gll16 (wave) instr
  __shared__ __bf16 As[BM][BK];
  __shared__ __bf16 Bs[128][BK];
  const int tid  = threadIdx.x;
  const int lane = tid & 63;
  const int w    = tid >> 6;
  const int wr   = w >> 1, wc = w & 1;
  const int rowBase = blockIdx.y * BM;
  const int colBase = blockIdx.x * 128;

  f32x4 acc[MR][4];
  #pragma unroll
  for (int i = 0; i < MR; ++i)
    #pragma unroll
    for (int j = 0; j < 4; ++j) { f32x4 z = {0.f,0.f,0.f,0.f}; acc[i][j] = z; }

  const int srow = lane / LPR;         // staging row within RPI-row group
  const int sk   = (lane % LPR) * 8;   // staging k element offset
  const int fr   = lane & 15;
  const int fk   = (lane >> 4) * 8;

  for (int k0 = 0; k0 < K; k0 += BK) {
    // stage A (BM x BK): BM/RPI/4 instrs per wave, each RPI rows x BK*2 B = 1024B
    #pragma unroll
    for (int i = 0; i < BM / RPI / 4; ++i) {
      const int r0 = w * (BM / 4) + i * RPI;
      gll16(A + (size_t)(rowBase + r0 + srow) * K + k0 + sk, &As[r0][0]);
    }
    // stage B (128 x BK): 128/RPI/4 instrs per wave
    #pragma unroll
    for (int i = 0; i < 128 / RPI / 4; ++i) {
      const int r0 = w * 32 + i * RPI;
      gll16(B + (size_t)(colBase + r0 + srow) * K + k0 + sk, &Bs[r0][0]);
    }
    __syncthreads();   // compiler drains vmcnt before s_barrier

    #pragma unroll
    for (int kk = 0; kk < BK / 32; ++kk) {
      bf16x8 af[MR], bfr[4];
      #pragma unroll
      for (int mm = 0; mm < MR; ++mm)
        af[mm] = *(const bf16x8*)&As[wr * (BM / 2) + mm * 16 + fr][kk * 32 + fk];
      #pragma unroll
      for (int nn = 0; nn < 4; ++nn)
        bfr[nn] = *(const bf16x8*)&Bs[wc * 64 + nn * 16 + fr][kk * 32 + fk];
      #pragma unroll
      for (int mm = 0; mm < MR; ++mm)
        #pragma unroll
        for (int nn = 0; nn < 4; ++nn)
          acc[mm][nn] = __builtin_amdgcn_mfma_f32_16x16x32_bf16(af[mm], bfr[nn], acc[mm][nn], 0, 0, 0);
    }
    __syncthreads();
  }

  // epilogue: C/D layout col=lane&15, row=(lane>>4)*4+reg  [verified m89/m91]
  #pragma unroll
  for (int nn = 0; nn < 4; ++nn) {
    int col = colBase + wc * 64 + nn * 16 + fr;
    float bv = bias[col];
    #pragma unroll
    for (int mm = 0; mm < MR; ++mm) {
      int row0 = rowBase + wr * (BM / 2) + mm * 16 + (lane >> 4) * 4;
      #pragma unroll
      for (int r = 0; r < 4; ++r)
        storeC(acc[mm][nn][r] + bv, &C[(size_t)(row0 + r) * N + col]);
    }
  }
}

// ---------------- causal depthwise conv (k=4) + bias + SiLU ----------------
// reads bf16 xar (xs branch, cols 0..2047), writes bf16 xs ONLY (8 MB).
__global__ __launch_bounds__(256) void conv_silu_kernel(
    const unsigned short* __restrict__ xar, const float* __restrict__ cw,
    const float* __restrict__ cb, unsigned short* __restrict__ xsbf) {
  int idx = blockIdx.x * 256 + threadIdx.x;     // one bf16x8 of d per thread
  int m  = idx >> 8;                            // row (b*1024 + t)
  int d8 = (idx & 255) << 3;                    // d offset (0..2040)
  int t  = m & (SEQ - 1);
  const __bf16* xarb = (const __bf16*)xar;

  float4 cwl[8];
  const float4* cw4 = (const float4*)cw;        // cw[d][0..3] contiguous
  #pragma unroll
  for (int e = 0; e < 8; ++e) cwl[e] = cw4[d8 + e];

  float acc[8];
  #pragma unroll
  for (int e = 0; e < 8; ++e) acc[e] = cb[d8 + e];

  #pragma unroll
  for (int j = 0; j < 4; ++j) {
    int tt = t - 3 + j;
    if (tt < 0) continue;                       // causal left zero-pad (per batch)
    bf16x8 v = *(const bf16x8*)&xarb[(size_t)(m - 3 + j) * (2 * D_INNER) + d8];
    const float* cj = (const float*)cwl;
    #pragma unroll
    for (int e = 0; e < 8; ++e)
      acc[e] += (float)v[e] * cj[e * 4 + j];
  }
  unsigned short o[8];
  #pragma unroll
  for (int e = 0; e < 8; ++e) {
    float s = acc[e] * sigmoid_fast(acc[e]);
    o[e] = f2bf(s);
  }
  *(ushort4*)&xsbf[(size_t)m * D_INNER + d8]     = *(ushort4*)&o[0];
  *(ushort4*)&xsbf[(size_t)m * D_INNER + d8 + 4] = *(ushort4*)&o[4];
}

// ---------------- x_proj via MFMA, K-SPLIT: [2048,48] = xs_bf @ xpw_bf^T + b ----------
// grid (32 row-tiles, 16 k-splits) = 512 blocks; partials atomicAdd'd into
// dlt/Bm/Cm (zero-initialized by cast_all). Bias added by ksplit 0 only.
__global__ __launch_bounds__(256) void xproj_mfma(
    const __bf16* __restrict__ A, const __bf16* __restrict__ B,
    const float* __restrict__ xpb,
    float* __restrict__ dlt, float* __restrict__ Bm, float* __restrict__ Cm) {
  __shared__ __bf16 As[64][32];
  __shared__ __bf16 Bs[48][32];
  const int tid  = threadIdx.x;
  const int lane = tid & 63;
  const int w    = tid >> 6;
  const int rowBase = blockIdx.x * 64;
  const int kbase   = blockIdx.y * XP_KLEN;

  f32x4 acc[3];
  #pragma unroll
  for (int j = 0; j < 3; ++j) { f32x4 z = {0.f,0.f,0.f,0.f}; acc[j] = z; }

  const int srow = lane >> 2;
  const int sk   = (lane & 3) * 8;
  const int fr   = lane & 15;
  const int fk   = (lane >> 4) * 8;

  for (int k0 = kbase; k0 < kbase + XP_KLEN; k0 += 32) {
    gll16(A + (size_t)(rowBase + w * 16 + srow) * D_INNER + k0 + sk, &As[w * 16][0]);
    if (w < 3)
      gll16(B + (size_t)(w * 16 + srow) * D_INNER + k0 + sk, &Bs[w * 16][0]);
    __syncthreads();
    bf16x8 af = *(const bf16x8*)&As[w * 16 + fr][fk];
    #pragma unroll
    for (int nn = 0; nn < 3; ++nn) {
      bf16x8 bv = *(const bf16x8*)&Bs[nn * 16 + fr][fk];
      acc[nn] = __builtin_amdgcn_mfma_f32_16x16x32_bf16(af, bv, acc[nn], 0, 0, 0);
    }
    __syncthreads();
  }

  // C/D layout: col = lane&15, row = (lane>>4)*4 + reg. Bias only from ksplit 0.
  const int c16 = lane & 15;
  const float biasOn = (blockIdx.y == 0) ? 1.f : 0.f;
  #pragma unroll
  for (int nn = 0; nn < 3; ++nn) {
    float bv = biasOn * xpb[nn * 16 + c16];
    float* dst = (nn == 0) ? dlt : (nn == 1) ? Bm : Cm;
    int row0 = rowBase + w * 16 + (lane >> 4) * 4;
    #pragma unroll
    for (int r = 0; r < 4; ++r)
      atomicAdd(&dst[(size_t)(row0 + r) * 16 + c16], acc[nn][r] + bv);
  }
}

// ======================= chunked parallel selective scan =======================
// Phase1: per-chunk local scan from h=0 -> Hbuf = local h_end, Sbuf = sum(dv).
// Phase2: sequential combine; Hbuf becomes TRUE h at chunk START (in-place).
// Phase3: replay from true h_start; fuse y, D-skip, gate, bf16 cast.

#define DELTA16(sarr, ttq)                                                       \
  {                                                                              \
    float4 q0 = *(const float4*)&sarr[ttq][0];                                   \
    float4 q1 = *(const float4*)&sarr[ttq][4];                                   \
    float4 q2 = *(const float4*)&sarr[ttq][8];                                   \
    float4 q3 = *(const float4*)&sarr[ttq][12];                                  \
    s += q0.x*dtwr[0] + q0.y*dtwr[1] + q0.z*dtwr[2] + q0.w*dtwr[3];              \
    s += q1.x*dtwr[4] + q1.y*dtwr[5] + q1.z*dtwr[6] + q1.w*dtwr[7];              \
    s += q2.x*dtwr[8] + q2.y*dtwr[9] + q2.z*dtwr[10] + q2.w*dtwr[11];            \
    s += q3.x*dtwr[12] + q3.y*dtwr[13] + q3.z*dtwr[14] + q3.w*dtwr[15];          \
  }

__global__ __launch_bounds__(256) void scan_phase1(
    const unsigned short* __restrict__ xsbf, const float* __restrict__ dlt,
    const float* __restrict__ Bmat, const float* __restrict__ dtw,
    const float* __restrict__ dtb, const float* __restrict__ alog,
    float* __restrict__ Hbuf, float* __restrict__ Sbuf) {
  __shared__ float dltS[CHUNK][16];
  __shared__ float BS[CHUNK][16];
  const int tid = threadIdx.x;
  const int c   = blockIdx.y;
  const int b   = blockIdx.z;
  const int d   = blockIdx.x * 256 + tid;
  const int row0 = b * SEQ + c * CHUNK;
  const __bf16* xsb16 = (const __bf16*)xsbf;
  {
    int e = tid * 2;
    int tt = e >> 4, r = e & 15;
    *(float2*)&dltS[tt][r] = *(const float2*)&dlt[(row0 + tt) * 16 + r];
    *(float2*)&BS[tt][r]   = *(const float2*)&Bmat[(row0 + tt) * 16 + r];
  }
  float dtwr[16], An[16];
  #pragma unroll
  for (int q = 0; q < 4; ++q) {
    float4 w4 = *(const float4*)&dtw[d * 16 + q * 4];
    dtwr[q*4+0] = w4.x; dtwr[q*4+1] = w4.y; dtwr[q*4+2] = w4.z; dtwr[q*4+3] = w4.w;
    float4 a4 = *(const float4*)&alog[d * 16 + q * 4];
    An[q*4+0] = -__expf(a4.x); An[q*4+1] = -__expf(a4.y);
    An[q*4+2] = -__expf(a4.z); An[q*4+3] = -__expf(a4.w);
  }
  const float dtbv = dtb[d];
  float xv[CHUNK];
  #pragma unroll
  for (int tt = 0; tt < CHUNK; ++tt)
    xv[tt] = (float)xsb16[(size_t)(row0 + tt) * D_INNER + d];
  __syncthreads();
  float dv[CHUNK];
  #pragma unroll
  for (int tt = 0; tt < CHUNK; ++tt) {
    float s = dtbv;
    DELTA16(dltS, tt);
    dv[tt] = softplus_f(s);
  }
  float h[16];
  #pragma unroll
  for (int n = 0; n < 16; ++n) h[n] = 0.f;
  float Ssum = 0.f;
  #pragma unroll
  for (int tt = 0; tt < CHUNK; ++tt) {
    const float dvt = dv[tt];
    Ssum += dvt;
    const float dvx = dvt * xv[tt];
    float4 B0 = *(const float4*)&BS[tt][0];
    float4 B1 = *(const float4*)&BS[tt][4];
    float4 B2 = *(const float4*)&BS[tt][8];
    float4 B3 = *(const float4*)&BS[tt][12];
    h[0]  = __expf(dvt*An[0])*h[0]   + dvx*B0.x;
    h[1]  = __expf(dvt*An[1])*h[1]   + dvx*B0.y;
    h[2]  = __expf(dvt*An[2])*h[2]   + dvx*B0.z;
    h[3]  = __expf(dvt*An[3])*h[3]   + dvx*B0.w;
    h[4]  = __expf(dvt*An[4])*h[4]   + dvx*B1.x;
    h[5]  = __expf(dvt*An[5])*h[5]   + dvx*B1.y;
    h[6]  = __expf(dvt*An[6])*h[6]   + dvx*B1.z;
    h[7]  = __expf(dvt*An[7])*h[7]   + dvx*B1.w;
    h[8]  = __expf(dvt*An[8])*h[8]   + dvx*B2.x;
    h[9]  = __expf(dvt*An[9])*h[9]   + dvx*B2.y;
    h[10] = __expf(dvt*An[10])*h[10] + dvx*B2.z;
    h[11] = __expf(dvt*An[11])*h[11] + dvx*B2.w;
    h[12] = __expf(dvt*An[12])*h[12] + dvx*B3.x;
    h[13] = __expf(dvt*An[13])*h[13] + dvx*B3.y;
    h[14] = __expf(dvt*An[14])*h[14] + dvx*B3.z;
    h[15] = __expf(dvt*An[15])*h[15] + dvx*B3.w;
  }
  size_t hbase = (((size_t)(b * NCHUNK + c) * D_INNER) + d) * 16;
  #pragma unroll
  for (int q = 0; q < 4; ++q) {
    float4 o = {h[q*4+0], h[q*4+1], h[q*4+2], h[q*4+3]};
    *(float4*)&Hbuf[hbase + q*4] = o;
  }
  Sbuf[((size_t)b * NCHUNK + c) * D_INNER + d] = Ssum;
}

__global__ __launch_bounds__(256) void scan_phase2(
    const float* __restrict__ alog, const float* __restrict__ Sbuf,
    float* __restrict__ Hbuf) {
  const int tid = threadIdx.x;
  const int n  = tid & 15;
  const int dl = tid >> 4;
  const int d  = blockIdx.x * 16 + dl;
  const int b  = blockIdx.y;
  const float An = -__expf(alog[d * 16 + n]);
  float h_run = 0.f;
  #pragma unroll 4
  for (int c = 0; c < NCHUNK; ++c) {
    size_t idx = (((size_t)(b * NCHUNK + c) * D_INNER) + d) * 16 + n;
    float hend = Hbuf[idx];
    float P = __expf(An * Sbuf[((size_t)b * NCHUNK + c) * D_INNER + d]);
    Hbuf[idx] = h_run;                     // h at chunk START
    h_run = P * h_run + hend;
  }
}

__global__ __launch_bounds__(256) void scan_phase3(
    const unsigned short* __restrict__ xsbf, const unsigned short* __restrict__ xar,
    const float* __restrict__ dlt, const float* __restrict__ Bmat,
    const float* __restrict__ Cmat, const float* __restrict__ dtw,
    const float* __restrict__ dtb, const float* __restrict__ alog,
    const float* __restrict__ Dvec, const float* __restrict__ Hbuf,
    unsigned short* __restrict__ ybf) {
  __shared__ float dltS[CHUNK][16];
  __shared__ float BS[CHUNK][16];
  __shared__ float CS[CHUNK][16];
  const int tid = threadIdx.x;
  const int c   = blockIdx.y;
  const int b   = blockIdx.z;
  const int d   = blockIdx.x * 256 + tid;
  const int row0 = b * SEQ + c * CHUNK;
  const __bf16* xsb16 = (const __bf16*)xsbf;
  const __bf16* xarb  = (const __bf16*)xar;
  {
    int e = tid * 2;
    int tt = e >> 4, r = e & 15;
    *(float2*)&dltS[tt][r] = *(const float2*)&dlt[(row0 + tt) * 16 + r];
    *(float2*)&BS[tt][r]   = *(const float2*)&Bmat[(row0 + tt) * 16 + r];
    *(float2*)&CS[tt][r]   = *(const float2*)&Cmat[(row0 + tt) * 16 + r];
  }
  float dtwr[16], An[16];
  #pragma unroll
  for (int q = 0; q < 4; ++q) {
    float4 w4 = *(const float4*)&dtw[d * 16 + q * 4];
    dtwr[q*4+0] = w4.x; dtwr[q*4+1] = w4.y; dtwr[q*4+2] = w4.z; dtwr[q*4+3] = w4.w;
    float4 a4 = *(const float4*)&alog[d * 16 + q * 4];
    An[q*4+0] = -__expf(a4.x); An[q*4+1] = -__expf(a4.y);
    An[q*4+2] = -__expf(a4.z); An[q*4+3] = -__expf(a4.w);
  }
  const float dtbv = dtb[d];
  const float Dn   = Dvec[d];
  float h[16];
  {
    size_t hbase = (((size_t)(b * NCHUNK + c) * D_INNER) + d) * 16;
    #pragma unroll
    for (int q = 0; q < 4; ++q) {
      float4 hv = *(const float4*)&Hbuf[hbase + q*4];
      h[q*4+0] = hv.x; h[q*4+1] = hv.y; h[q*4+2] = hv.z; h[q*4+3] = hv.w;
    }
  }
  float xv[CHUNK], rv[CHUNK];
  #pragma unroll
  for (int tt = 0; tt < CHUNK; ++tt) {
    xv[tt] = (float)xsb16[(size_t)(row0 + tt) * D_INNER + d];
    rv[tt] = (float)xarb[(size_t)(row0 + tt) * (2 * D_INNER) + D_INNER + d];
  }
  __syncthreads();
  float dv[CHUNK];
  #pragma unroll
  for (int tt = 0; tt < CHUNK; ++tt) {
    float s = dtbv;
    DELTA16(dltS, tt);
    dv[tt] = softplus_f(s);
  }
  #pragma unroll
  for (int tt = 0; tt < CHUNK; ++tt) {
    const float dvt = dv[tt];
    const float dvx = dvt * xv[tt];
    float4 B0 = *(const float4*)&BS[tt][0];
    float4 B1 = *(const float4*)&BS[tt][4];
    float4 B2 = *(const float4*)&BS[tt][8];
    float4 B3 = *(const float4*)&BS[tt][12];
    float4 C0 = *(const float4*)&CS[tt][0];
    float4 C1 = *(const float4*)&CS[tt][4];
    float4 C2 = *(const float4*)&CS[tt][8];
    float4 C3 = *(const float4*)&CS[tt][12];
    float y = 0.f;
    h[0]  = __expf(dvt*An[0])*h[0]   + dvx*B0.x;  y += h[0]*C0.x;
    h[1]  = __expf(dvt*An[1])*h[1]   + dvx*B0.y;  y += h[1]*C0.y;
    h[2]  = __expf(dvt*An[2])*h[2]   + dvx*B0.z;  y += h[2]*C0.z;
    h[3]  = __expf(dvt*An[3])*h[3]   + dvx*B0.w;  y += h[3]*C0.w;
    h[4]  = __expf(dvt*An[4])*h[4]   + dvx*B1.x;  y += h[4]*C1.x;
    h[5]  = __expf(dvt*An[5])*h[5]   + dvx*B1.y;  y += h[5]*C1.y;
    h[6]  = __expf(dvt*An[6])*h[6]   + dvx*B1.z;  y += h[6]*C1.z;
    h[7]  = __expf(dvt*An[7])*h[7]   + dvx*B1.w;  y += h[7]*C1.w;
    h[8]  = __expf(dvt*An[8])*h[8]   + dvx*B2.x;  y += h[8]*C2.x;
    h[9]  = __expf(dvt*An[9])*h[9]   + dvx*B2.y;  y += h[9]*C2.y;
    h[10] = __expf(dvt*An[10])*h[10] + dvx*B2.z;  y += h[10]*C2.z;
    h[11] = __expf(dvt*An[11])*h[11] + dvx*B2.w;  y += h[11]*C2.w;
    h[12] = __expf(dvt*An[12])*h[12] + dvx*B3.x;  y += h[12]*C3.x;
    h[13] = __expf(dvt*An[13])*h[13] + dvx*B3.y;  y += h[13]*C3.y;
    h[14] = __expf(dvt*An[14])*h[14] + dvx*B3.z;  y += h[14]*C3.z;
    h[15] = __expf(dvt*An[15])*h[15] + dvx*B3.w;  y += h[15]*C3.w;
    y += xv[tt] * Dn;
    const float r = rv[tt];
    const float v = y * (r * sigmoid_fast(r));
    ybf[(size_t)(row0 + tt) * D_INNER + d] = f2bf(v);
  }
}

// ---------------- launcher ----------------
extern "C" void kernel_launch(void* const* d_in, const int* in_sizes, int n_in,
                              void* d_out, int out_size, void* d_ws, size_t ws_size,
                              hipStream_t stream) {
  const float* x    = (const float*)d_in[0];
  const float* ipw  = (const float*)d_in[1];
  const float* ipb  = (const float*)d_in[2];
  const float* cw   = (const float*)d_in[3];
  const float* cb   = (const float*)d_in[4];
  const float* xpw  = (const float*)d_in[5];
  const float* xpb  = (const float*)d_in[6];
  const float* dtw  = (const float*)d_in[7];
  const float* dtb  = (const float*)d_in[8];
  const float* alog = (const float*)d_in[9];
  const float* Dv   = (const float*)d_in[10];
  const float* opw  = (const float*)d_in[11];
  const float* opb  = (const float*)d_in[12];
  float* out = (float*)d_out;

  char* ws = (char*)d_ws;
  size_t off = 0;
  auto alloc = [&](size_t bytes) {
    char* p = ws + off;
    off += (bytes + 255) & ~(size_t)255;
    return p;
  };
  unsigned short* xbf   = (unsigned short*)alloc((size_t)M_ROWS * D_MODEL * 2);       // 4 MB
  unsigned short* w1bf  = (unsigned short*)alloc((size_t)2 * D_INNER * D_MODEL * 2);  // 8 MB
  unsigned short* w2bf  = (unsigned short*)alloc((size_t)D_MODEL * D_INNER * 2);      // 4 MB
  unsigned short* xpwbf = (unsigned short*)alloc((size_t)48 * D_INNER * 2);           // 192 KB
  unsigned short* xar   = (unsigned short*)alloc((size_t)M_ROWS * 2 * D_INNER * 2);   // 16 MB bf16
  unsigned short* xsbf  = (unsigned short*)alloc((size_t)M_ROWS * D_INNER * 2);       // 8 MB
  float* dlt = (float*)alloc((size_t)M_ROWS * 16 * 4);   // 128 KB  } contiguous
  float* Bm  = (float*)alloc((size_t)M_ROWS * 16 * 4);   // 128 KB  } 384 KB zeroed
  float* Cm  = (float*)alloc((size_t)M_ROWS * 16 * 4);   // 128 KB  } by cast_all
  unsigned short* ybf = (unsigned short*)alloc((size_t)M_ROWS * D_INNER * 2);         // 8 MB
  if (off > ws_size) return;
  // w1bf region (8 MB) is dead after gemm1; reused for Hbuf (phase1 -> phase3).
  float* Hbuf = (float*)w1bf;   // [B][NCHUNK][D_INNER][16] f32 = 8 MB exactly
  float* Sbuf = (float*)xbf;    // xbf dead after gemm1; Sbuf = 512 KB

  // 1. casts + zero dlt/Bm/Cm. Grid: (524288+1048576+524288+24576+24576)/256 = 8384
  cast_all_kernel<<<8384, 256, 0, stream>>>(x, ipw, opw, xpw, xbf, w1bf, w2bf, xpwbf, dlt);
  // 2. in_proj -> bf16 xar; BK=64 (16 K-iters)
  gemm_gll<128, 64, unsigned short><<<dim3(4096 / 128, 2048 / 128), 256, 0, stream>>>(
      (const __bf16*)xbf, (const __bf16*)w1bf, ipb, xar, M_ROWS, 2 * D_INNER, D_MODEL);
  // 3. conv + silu: bf16 in, bf16 out
  conv_silu_kernel<<<2048, 256, 0, stream>>>(xar, cw, cb, xsbf);
  // 4. x_proj via K-split MFMA + atomics: grid (32, 16) = 512 blocks
  xproj_mfma<<<dim3(M_ROWS / 64, XP_KSPLIT), 256, 0, stream>>>(
      (const __bf16*)xsbf, (const __bf16*)xpwbf, xpb, dlt, Bm, Cm);
  // 5. chunked scan (3 phases)
  scan_phase1<<<dim3(D_INNER / 256, NCHUNK, BATCH), 256, 0, stream>>>(
      xsbf, dlt, Bm, dtw, dtb, alog, Hbuf, Sbuf);
  scan_phase2<<<dim3(D_INNER / 16, BATCH), 256, 0, stream>>>(alog, Sbuf, Hbuf);
  scan_phase3<<<dim3(D_INNER / 256, NCHUNK, BATCH), 256, 0, stream>>>(
      xsbf, xar, dlt, Bm, Cm, dtw, dtb, alog, Dv, Hbuf, ybf);
  // 6. out_proj: 64x128 tiles, BK=64 (32 K-iters), 256 wgs, f32 out
  gemm_gll<64, 64, float><<<dim3(1024 / 128, 2048 / 64), 256, 0, stream>>>(
      (const __bf16*)ybf, (const __bf16*)w2bf, opb, out, M_ROWS, D_MODEL, D_INNER);
}